// Round 9
// baseline (95.302 us; speedup 1.0000x reference)
//
#include <hip/hip_runtime.h>
#include <hip/hip_bf16.h>
#include <math.h>

// MEASUREMENT ROUND: identical to R7 kernel, but grid doubled (4000 blocks);
// blocks 2000..3999 redo cells 0..7999 writing identical values. This makes
// the fused_mfma dispatch ~2T (> the 42us harness fills) so it surfaces in
// the top-5 rocprof rows with full counters, and dur_us - 82 = T exactly.
//
// Fused ConvTranspose3d(16->32, K=3, s=2, p=1) + MaxPool3d(6) + channel-sum,
// MFMA edition. One WAVE per pooled cell. Per class c, y[27pos x 32co] =
// sum_{taps} A_t*B_t via v_mfma_f32_32x32x16_bf16 (27 MFMAs total).
// D layout (m74/m101): col = lane&31 (=co), row = (reg&3)+8*(reg>>2)+4*hi.

namespace {

typedef __attribute__((ext_vector_type(8))) short short8;
typedef __attribute__((ext_vector_type(16))) float f32x16;

// class-ordered tap -> kd*9+kh*3+kw; class c=PA*4+PB*2+PC, within-class
// (a,b,c) with a==0 -> k=0, a==1 -> k=2 on P=1 axes. bases {0,1,3,5,9,11,15,19}
__constant__ int JK[27] = {13, 12, 14, 10, 16, 9,  11, 15, 17, 4,  22, 3,  5, 21,
                           23, 1,  7,  19, 25, 0,  2,  6,  8,  18, 20, 24, 26};

__device__ __forceinline__ uint f2bf(float f) {
  uint u = __float_as_uint(f);
  return (u + 0x7FFFu + ((u >> 16) & 1u)) >> 16;  // RNE bf16 bits
}

__global__ void prep_w(const float* __restrict__ w, ushort* __restrict__ w2) {
  const int o = blockIdx.x * 256 + threadIdx.x;  // 27*2*32*8 = 13824
  const int t2 = o >> 9;         // class-ordered tap
  const int cih = (o >> 8) & 1;  // k-half
  const int co = (o >> 3) & 31;
  const int ci = cih * 8 + (o & 7);
  w2[o] = (ushort)f2bf(w[(ci * 32 + co) * 27 + JK[t2]]);
}

template <int PA, int PB, int PC, int BASE>
__device__ __forceinline__ float cls_max(const ushort* __restrict__ w2l,
                                         const char* __restrict__ xw, int lin0,
                                         int lin1, int sz0, int sz1, int hi) {
  constexpr int NTZ = PA ? 2 : 1, NTY = PB ? 2 : 1, NTX = PC ? 2 : 1;
  constexpr int NT = NTZ * NTY * NTX;
  short8 bv[NT];
#pragma unroll
  for (int t = 0; t < NT; ++t)
    bv[t] = *reinterpret_cast<const short8*>(w2l + (BASE + t) * 512);

  f32x16 d;
#pragma unroll
  for (int i = 0; i < 16; ++i) d[i] = 0.f;
#pragma unroll
  for (int a = 0; a < NTZ; ++a) {
    const int oz = PA ? (a ? 0 : 1) : 0;
#pragma unroll
    for (int b = 0; b < NTY; ++b) {
      const int oy = PB ? (b ? 0 : 1) : 0;
#pragma unroll
      for (int c = 0; c < NTX; ++c) {
        const int ox = PC ? (c ? 0 : 1) : 0;
        // XOR swizzle applied AFTER the linear tap offset (oy,ox stay in-plane)
        const int addr =
            ((oz ? lin1 : lin0) + (oy * 4 + ox) * 48) ^ (oz ? sz1 : sz0);
        const short8 av = *reinterpret_cast<const short8*>(xw + addr);
        d = __builtin_amdgcn_mfma_f32_32x32x16_bf16(
            av, bv[(a * NTY + b) * NTX + c], d, 0, 0, 0);
      }
    }
  }
  // max over valid rows: regs 0..11 valid both halves; 12..14 only hi==0.
  float ma = d[0];
#pragma unroll
  for (int i = 1; i < 12; ++i) ma = fmaxf(ma, d[i]);
  const float mb = fmaxf(d[12], fmaxf(d[13], d[14]));
  return hi ? ma : fmaxf(ma, mb);
}

__global__ __launch_bounds__(256, 4) void fused_mfma(
    const float* __restrict__ x, const ushort* __restrict__ w2,
    const float* __restrict__ bias, float* __restrict__ out) {
  __shared__ __align__(16) char xls[4 * 3072];

  const int t = threadIdx.x;
  const int wv = t >> 6;
  const int l = t & 63;
  const int hi = l >> 5;
  const int co = l & 31;

  const int bd = blockIdx.x >= 2000 ? blockIdx.x - 2000 : blockIdx.x;
  const int cell = bd * 4 + wv;
  const int pw = cell % 10;
  const int ph = (cell / 10) % 10;
  const int pd = (cell / 100) % 10;
  const int n = cell / 1000;

  // stage this wave's 4^3 x-window: lane = spatial g, gathers its 16 ci
  char* xw = xls + wv * 3072;
  {
    const int xi = l & 3, yi = (l >> 2) & 3, zi = l >> 4;
    const float* xg = x + (size_t)n * 524288 + (size_t)(3 * pd + zi) * 1024 +
                      (3 * ph + yi) * 32 + (3 * pw + xi);
    uint pk[8];
#pragma unroll
    for (int q = 0; q < 8; ++q) {
      const uint h0 = f2bf(xg[(2 * q) * 32768]);
      const uint h1 = f2bf(xg[(2 * q + 1) * 32768]);
      pk[q] = (h0 & 0xFFFFu) | (h1 << 16);
    }
    const int swz = (zi & 3) << 4;
    const int a0 = (l * 48) ^ swz;       // ci 0..7
    const int a1 = (l * 48 + 16) ^ swz;  // ci 8..15
    *reinterpret_cast<uint4*>(xw + a0) = make_uint4(pk[0], pk[1], pk[2], pk[3]);
    *reinterpret_cast<uint4*>(xw + a1) = make_uint4(pk[4], pk[5], pk[6], pk[7]);
  }
  // wave-internal RAW on LDS (no cross-wave sharing): drain writes
  asm volatile("s_waitcnt lgkmcnt(0)" ::: "memory");

  // per-lane A base addresses: position p = lane&31 (rows 27..31 dup p=26)
  int p = co > 26 ? 26 : co;
  const int ip = p / 9, jp = (p / 3) % 3, kp = p % 3;
  const int lin0 = (ip * 16 + jp * 4 + kp) * 48 + hi * 16;        // oz = 0
  const int lin1 = ((ip + 1) * 16 + jp * 4 + kp) * 48 + hi * 16;  // oz = 1
  const int sz0 = (ip & 3) << 4;
  const int sz1 = ((ip + 1) & 3) << 4;

  const ushort* w2l = w2 + hi * 256 + co * 8;

  float cm = cls_max<1, 1, 1, 19>(w2l, xw, lin0, lin1, sz0, sz1, hi);
  cm = fmaxf(cm, cls_max<1, 1, 0, 15>(w2l, xw, lin0, lin1, sz0, sz1, hi));
  cm = fmaxf(cm, cls_max<1, 0, 1, 11>(w2l, xw, lin0, lin1, sz0, sz1, hi));
  cm = fmaxf(cm, cls_max<1, 0, 0, 9>(w2l, xw, lin0, lin1, sz0, sz1, hi));
  cm = fmaxf(cm, cls_max<0, 1, 1, 5>(w2l, xw, lin0, lin1, sz0, sz1, hi));
  cm = fmaxf(cm, cls_max<0, 1, 0, 3>(w2l, xw, lin0, lin1, sz0, sz1, hi));
  cm = fmaxf(cm, cls_max<0, 0, 1, 1>(w2l, xw, lin0, lin1, sz0, sz1, hi));
  cm = fmaxf(cm, cls_max<0, 0, 0, 0>(w2l, xw, lin0, lin1, sz0, sz1, hi));
  cm = fmaxf(cm, __shfl_xor(cm, 32));  // combine row-halves (same col)

  // + bias, then sum over the 32 channels (both halves hold identical data)
  float r = cm + bias[co];
#pragma unroll
  for (int off = 16; off >= 1; off >>= 1) r += __shfl_xor(r, off);
  if (l == 0) out[cell] = r;  // duplicate blocks write identical values
}

}  // namespace

extern "C" void kernel_launch(void* const* d_in, const int* in_sizes, int n_in,
                              void* d_out, int out_size, void* d_ws,
                              size_t ws_size, hipStream_t stream) {
  const float* x = (const float*)d_in[0];
  const float* w = (const float*)d_in[1];
  const float* b = (const float*)d_in[2];
  float* out = (float*)d_out;
  ushort* w2 = (ushort*)d_ws;  // 13824 ushort = 27648 B
  prep_w<<<54, 256, 0, stream>>>(w, w2);
  fused_mfma<<<4000, 256, 0, stream>>>(x, w2, b, out);  // 2x duplicated work
}

// Round 10
// 80.327 us; speedup vs baseline: 1.1864x; 1.1864x over previous
//
#include <hip/hip_runtime.h>
#include <math.h>

// Fused ConvTranspose3d(16->32, K=3, s=2, p=1) + MaxPool3d(6) + channel-sum.
// ROW-BLOCK MFMA edition: block = (n, pd, ph) row of 10 pooled cells
// (800 blocks x 256 thr, all co-resident). Staging reads ENTIRE 128B x-rows
// coalesced (kills R5's 3.7x line over-fetch: 62 MB -> ~17 MB distinct).
// Work: 40 units = (set s, cell c), unit u = s*10+c assigned to wave u&3
// (69/69/66/66 taps). Sets are complement class-pairs {7,0},{6,1},{5,2},{3,4}.
// Per tap: one v_mfma_f32_32x32x16_bf16, A[27pos x 16ci] from swizzled LDS,
// B[16ci x 32co] from prep'd w2 (L1-hot). D layout (m74/m101): col=lane&31=co,
// row=(reg&3)+8*(reg>>2)+4*hi. Partial (cell,set) maxes -> LDS -> final pass.
// LDS x layout: byte(z,y,xcol,ci) = (z<<12)+(y<<10)+(xcol<<5)+((ci>>3)<<4)
// +((ci&7)<<1), XOR'd by (((z*4+y)^(xcol>>2))&7)<<4 (same formula on write
// and read -> bijective; spreads the 16B slots across banks).

namespace {

typedef __attribute__((ext_vector_type(8))) short short8;
typedef __attribute__((ext_vector_type(16))) float f32x16;

// class-ordered tap -> kd*9+kh*3+kw; class c=PA*4+PB*2+PC, within-class
// (a,b,c) with a==0 -> k=0, a==1 -> k=2 on P=1 axes. bases {0,1,3,5,9,11,15,19}
__constant__ int JK[27] = {13, 12, 14, 10, 16, 9,  11, 15, 17, 4,  22, 3,  5, 21,
                           23, 1,  7,  19, 25, 0,  2,  6,  8,  18, 20, 24, 26};

__device__ __forceinline__ uint f2bf(float f) {
  uint u = __float_as_uint(f);
  return (u + 0x7FFFu + ((u >> 16) & 1u)) >> 16;  // RNE bf16 bits
}

__global__ void prep_w(const float* __restrict__ w, ushort* __restrict__ w2) {
  const int o = blockIdx.x * 256 + threadIdx.x;  // 27*2*32*8 = 13824
  const int t2 = o >> 9;         // class-ordered tap
  const int cih = (o >> 8) & 1;  // k-half
  const int co = (o >> 3) & 31;
  const int ci = cih * 8 + (o & 7);
  w2[o] = (ushort)f2bf(w[(ci * 32 + co) * 27 + JK[t2]]);
}

struct Pre {
  uint a[2][2][2];  // [oz][oy][ox] -- always accessed with constexpr indices
};

__device__ __forceinline__ f32x16 zero16() {
  f32x16 d;
#pragma unroll
  for (int i = 0; i < 16; ++i) d[i] = 0.f;
  return d;
}

template <int CC, int BASE>
__device__ __forceinline__ void class_accum(f32x16& d,
                                            const ushort* __restrict__ w2l,
                                            const Pre& pre,
                                            const char* __restrict__ xb) {
  constexpr int PA = (CC >> 2) & 1, PB = (CC >> 1) & 1, PC = CC & 1;
  constexpr int NTZ = PA ? 2 : 1, NTY = PB ? 2 : 1, NTX = PC ? 2 : 1;
#pragma unroll
  for (int a = 0; a < NTZ; ++a) {
    const int oz = PA ? (a ? 0 : 1) : 0;
#pragma unroll
    for (int b = 0; b < NTY; ++b) {
      const int oy = PB ? (b ? 0 : 1) : 0;
#pragma unroll
      for (int c = 0; c < NTX; ++c) {
        const int ox = PC ? (c ? 0 : 1) : 0;
        const short8 bv = *reinterpret_cast<const short8*>(
            w2l + (BASE + (a * NTY + b) * NTX + c) * 512);
        const short8 av =
            *reinterpret_cast<const short8*>(xb + pre.a[oz][oy][ox]);
        d = __builtin_amdgcn_mfma_f32_32x32x16_bf16(av, bv, d, 0, 0, 0);
      }
    }
  }
}

__device__ __forceinline__ float rowmax(const f32x16& d, int hi) {
  // rows: (reg&3)+8*(reg>>2)+4*hi; valid rows < 27 -> regs 0..11 both halves,
  // regs 12..14 only hi==0, reg 15 never.
  float ma = d[0];
#pragma unroll
  for (int i = 1; i < 12; ++i) ma = fmaxf(ma, d[i]);
  const float mb = fmaxf(fmaxf(d[12], d[13]), d[14]);
  return hi ? ma : fmaxf(ma, mb);
}

// SP=0: sets {0:(7,0), 2:(5,2)};  SP=1: sets {1:(6,1), 3:(3,4)}
template <int SP>
__device__ __forceinline__ void do_cell(int pw, int l, int hi, int co, int kp,
                                        const uint lin[2][2],
                                        const int zy4[2][2],
                                        const ushort* __restrict__ w2l,
                                        const ushort* __restrict__ xs,
                                        float* __restrict__ red) {
  Pre pre;
  const int cellk = 3 * pw + kp;
#pragma unroll
  for (int oz = 0; oz < 2; ++oz)
#pragma unroll
    for (int oy = 0; oy < 2; ++oy)
#pragma unroll
      for (int ox = 0; ox < 2; ++ox) {
        const int xcol = cellk + ox;
        pre.a[oz][oy][ox] = (lin[oz][oy] + (uint)(xcol << 5)) ^
                            ((uint)(((zy4[oz][oy] ^ (xcol >> 2)) & 7)) << 4);
      }
  const char* xb = reinterpret_cast<const char*>(xs);

  f32x16 d = zero16();
  if (SP == 0) class_accum<7, 19>(d, w2l, pre, xb);
  else         class_accum<6, 15>(d, w2l, pre, xb);
  float m = rowmax(d, hi);
  d = zero16();
  if (SP == 0) class_accum<0, 0>(d, w2l, pre, xb);
  else         class_accum<1, 1>(d, w2l, pre, xb);
  m = fmaxf(m, rowmax(d, hi));
  m = fmaxf(m, __shfl_xor(m, 32));
  if (l < 32) red[(pw * 4 + (SP == 0 ? 0 : 1)) * 32 + co] = m;

  d = zero16();
  if (SP == 0) class_accum<5, 11>(d, w2l, pre, xb);
  else         class_accum<3, 5>(d, w2l, pre, xb);
  m = rowmax(d, hi);
  d = zero16();
  if (SP == 0) class_accum<2, 3>(d, w2l, pre, xb);
  else         class_accum<4, 9>(d, w2l, pre, xb);
  m = fmaxf(m, rowmax(d, hi));
  m = fmaxf(m, __shfl_xor(m, 32));
  if (l < 32) red[(pw * 4 + (SP == 0 ? 2 : 3)) * 32 + co] = m;
}

__global__ __launch_bounds__(256, 4) void fused_mfma(
    const float* __restrict__ x, const ushort* __restrict__ w2,
    const float* __restrict__ bias, float* __restrict__ out) {
  __shared__ __align__(16) ushort xs[8192];  // 16 KB swizzled [z][y][xcol][ci]
  __shared__ float red[10 * 4 * 32];         // 5 KB partial (cell,set) maxes

  const int t = threadIdx.x;
  const int wv = t >> 6;
  const int l = t & 63;
  const int hi = l >> 5;
  const int co = l & 31;

  // chunked bijective XCD swizzle (800 = 8 * 100)
  const int lb = (blockIdx.x & 7) * 100 + (blockIdx.x >> 3);
  const int n = lb / 100, pd = (lb / 10) % 10, ph = lb % 10;

  // ---- stage: 16ci x 4z x 4y x 32xcol floats, coalesced float4 rows ----
  {
    const float* xg =
        x + (size_t)n * 524288 + (size_t)(3 * pd) * 1024 + (3 * ph) * 32;
#pragma unroll
    for (int j = 0; j < 8; ++j) {
      const int fi = j * 256 + t;  // float4 index, 2048 total
      const int r = fi >> 3;       // row 0..255 = (ci,z,y)
      const int xq = fi & 7;
      const int ci = r >> 4, z = (r >> 2) & 3, y = r & 3;
      const float4 v = *reinterpret_cast<const float4*>(
          xg + (size_t)ci * 32768 + z * 1024 + y * 32 + xq * 4);
      const uint base = (uint)((z << 12) + (y << 10) + ((ci >> 3) << 4) +
                               ((ci & 7) << 1));
      const uint swz = (uint)((((z * 4 + y) ^ xq) & 7)) << 4;
      char* xb = reinterpret_cast<char*>(xs);
      *(ushort*)(xb + ((base + ((uint)(4 * xq + 0) << 5)) ^ swz)) =
          (ushort)f2bf(v.x);
      *(ushort*)(xb + ((base + ((uint)(4 * xq + 1) << 5)) ^ swz)) =
          (ushort)f2bf(v.y);
      *(ushort*)(xb + ((base + ((uint)(4 * xq + 2) << 5)) ^ swz)) =
          (ushort)f2bf(v.z);
      *(ushort*)(xb + ((base + ((uint)(4 * xq + 3) << 5)) ^ swz)) =
          (ushort)f2bf(v.w);
    }
  }
  __syncthreads();

  // ---- per-lane A geometry: position p = lane&31 (rows 27..31 dup 26) ----
  const int p = co > 26 ? 26 : co;
  const int ip = p / 9, jp = (p / 3) % 3, kp = p % 3;
  uint lin[2][2];
  int zy4[2][2];
#pragma unroll
  for (int oz = 0; oz < 2; ++oz)
#pragma unroll
    for (int oy = 0; oy < 2; ++oy) {
      const int z = ip + oz, y = jp + oy;
      lin[oz][oy] = (uint)((z << 12) + (y << 10) + (hi << 4));
      zy4[oz][oy] = z * 4 + y;
    }

  const ushort* w2l = w2 + hi * 256 + co * 8;

  // group X: cells c ≡ wv (mod 4) -> sets {0,2}
  for (int c = wv; c < 10; c += 4)
    do_cell<0>(c, l, hi, co, kp, lin, zy4, w2l, xs, red);
  // group Y: cells c ≡ wv+2 (mod 4) -> sets {1,3}
  for (int c = (wv + 2) & 3; c < 10; c += 4)
    do_cell<1>(c, l, hi, co, kp, lin, zy4, w2l, xs, red);

  __syncthreads();

  // ---- final: max over 4 sets, +bias, channel-sum ----
  for (int c = wv; c < 10; c += 4) {
    float v = red[(c * 4 + 0) * 32 + co];
#pragma unroll
    for (int s = 1; s < 4; ++s) v = fmaxf(v, red[(c * 4 + s) * 32 + co]);
    v += bias[co];
#pragma unroll
    for (int off = 16; off >= 1; off >>= 1) v += __shfl_xor(v, off);
    if (l == 0) out[lb * 10 + c] = v;
  }
}

}  // namespace

extern "C" void kernel_launch(void* const* d_in, const int* in_sizes, int n_in,
                              void* d_out, int out_size, void* d_ws,
                              size_t ws_size, hipStream_t stream) {
  const float* x = (const float*)d_in[0];
  const float* w = (const float*)d_in[1];
  const float* b = (const float*)d_in[2];
  float* out = (float*)d_out;
  ushort* w2 = (ushort*)d_ws;  // 13824 ushort = 27648 B
  prep_w<<<54, 256, 0, stream>>>(w, w2);
  fused_mfma<<<800, 256, 0, stream>>>(x, w2, b, out);
}